// Round 3
// baseline (192.778 us; speedup 1.0000x reference)
//
#include <hip/hip_runtime.h>

// LJ pair-energy sum, round 6:
//  Rounds 4-5 post-mortem: compiler refuses register-held gather MLP
//  (VGPR stuck at 40 => ~4 loads in flight; 90 us unchanged).
//  New mechanism: global_load_lds gathers. Per-lane GLOBAL address is legal;
//  LDS dest = wave-uniform base + lane*16. Issue-and-forget: no result VGPRs,
//  so the compiler cannot re-serialize. 8 wave-loads outstanding per wave,
//  20 waves/CU (32 KB LDS/block) -> thousands of lane-gathers in flight.
//  Target: L2-transaction floor ~31 us for the pair kernel.

typedef int  vint4  __attribute__((ext_vector_type(4)));

__device__ __forceinline__ void gather16_to_lds(const float4* g, const float4* l)
{
    // int-casts dodge the generic->AS cast restriction (CK's idiom);
    // AS3 pointers are 32-bit, LDS offset lives in the low 32 bits.
    __builtin_amdgcn_global_load_lds(
        (const __attribute__((address_space(1))) void*)(uintptr_t)g,
        (__attribute__((address_space(3))) void*)(uint32_t)(uintptr_t)l,
        16, 0, 0);
}

__global__ __launch_bounds__(256) void repack_kernel(
    const float* __restrict__ x, float* __restrict__ xp, int n3)
{
    int t = blockIdx.x * 256 + threadIdx.x;
    if (t < n3) {
        float v = x[t];
        int p = t / 3;
        int c = t - 3 * p;
        xp[4 * p + c] = v;       // .w never read
    }
}

// 4 pairs/thread; 8 gathers per thread staged through LDS via global_load_lds.
__global__ __launch_bounds__(256) void lj_gld_kernel(
    const float4* __restrict__ xp,
    const float* __restrict__ eps_p,
    const float* __restrict__ sig_p,
    const float* __restrict__ box_p,
    const vint4* __restrict__ idx_i4,
    const vint4* __restrict__ idx_j4,
    double*      __restrict__ partial)
{
    // [wave][slot][lane] : 4*8*64*16 B = 32 KB. Per-wave private regions,
    // so no __syncthreads is needed around staging.
    __shared__ float4 stage[4][8][64];

    const int t    = blockIdx.x * blockDim.x + threadIdx.x;
    const int lane = threadIdx.x & 63;
    const int wid  = threadIdx.x >> 6;

    // index streams: non-temporal (stream-once; keep L2 for the position table)
    const vint4 ii = __builtin_nontemporal_load(idx_i4 + t);
    const vint4 jj = __builtin_nontemporal_load(idx_j4 + t);
    const int ia[4] = {ii.x, ii.y, ii.z, ii.w};
    const int ja[4] = {jj.x, jj.y, jj.z, jj.w};

    // Issue all 8 gathers; no result registers, nothing to serialize.
#pragma unroll
    for (int k = 0; k < 4; ++k)
        gather16_to_lds(xp + ia[k], &stage[wid][k][0]);
#pragma unroll
    for (int k = 0; k < 4; ++k)
        gather16_to_lds(xp + ja[k], &stage[wid][4 + k][0]);

    // scalar params while the gathers fly
    const float eps  = eps_p[0];
    const float sig  = sig_p[0];
    const float sig2 = sig * sig;
    const float L0 = box_p[0], L1 = box_p[1], L2 = box_p[2];
    const float i0 = 1.0f / L0, i1 = 1.0f / L1, i2 = 1.0f / L2;

    // drain this wave's gathers, then hard fence (rule #18)
    asm volatile("s_waitcnt vmcnt(0)" ::: "memory");
    __builtin_amdgcn_sched_barrier(0);

    float sum = 0.0f;
#pragma unroll
    for (int k = 0; k < 4; ++k) {
        const float4 pi = stage[wid][k][lane];
        const float4 pj = stage[wid][4 + k][lane];
        float dx = pi.x - pj.x;
        float dy = pi.y - pj.y;
        float dz = pi.z - pj.z;
        // jnp.round == round-half-even == rintf (RNE)
        dx -= L0 * rintf(dx * i0);
        dy -= L1 * rintf(dy * i1);
        dz -= L2 * rintf(dz * i2);
        const float r2 = dx * dx + dy * dy + dz * dz;
        const float s2 = sig2 / r2;
        const float s6 = s2 * s2 * s2;
        sum += s6 * s6 - s6;
    }
    double dsum = (double)(4.0f * eps * sum);

    #pragma unroll
    for (int off = 32; off > 0; off >>= 1)
        dsum += __shfl_down(dsum, off, 64);

    __shared__ double wsum[4];
    if ((threadIdx.x & 63) == 0) wsum[threadIdx.x >> 6] = dsum;
    __syncthreads();
    if (threadIdx.x == 0)
        partial[blockIdx.x] = wsum[0] + wsum[1] + wsum[2] + wsum[3];
}

// fallback: unpacked float3 gathers (only if ws too small to repack)
__global__ __launch_bounds__(256) void lj_pairs3_kernel(
    const float* __restrict__ x,
    const float* __restrict__ eps_p,
    const float* __restrict__ sig_p,
    const float* __restrict__ box_p,
    const vint4* __restrict__ idx_i4,
    const vint4* __restrict__ idx_j4,
    double*      __restrict__ partial)
{
    const int t = blockIdx.x * blockDim.x + threadIdx.x;
    const float eps  = eps_p[0];
    const float sig  = sig_p[0];
    const float sig2 = sig * sig;
    const float L0 = box_p[0], L1 = box_p[1], L2 = box_p[2];
    const float i0 = 1.0f / L0, i1 = 1.0f / L1, i2 = 1.0f / L2;

    const vint4 ii = __builtin_nontemporal_load(idx_i4 + t);
    const vint4 jj = __builtin_nontemporal_load(idx_j4 + t);
    const int ia[4] = {ii.x, ii.y, ii.z, ii.w};
    const int ja[4] = {jj.x, jj.y, jj.z, jj.w};

    float sum = 0.0f;
#pragma unroll
    for (int k = 0; k < 4; ++k) {
        const float* pi = x + 3 * ia[k];
        const float* pj = x + 3 * ja[k];
        float dx = pi[0] - pj[0];
        float dy = pi[1] - pj[1];
        float dz = pi[2] - pj[2];
        dx -= L0 * rintf(dx * i0);
        dy -= L1 * rintf(dy * i1);
        dz -= L2 * rintf(dz * i2);
        const float r2 = dx * dx + dy * dy + dz * dz;
        const float s2 = sig2 / r2;
        const float s6 = s2 * s2 * s2;
        sum += s6 * s6 - s6;
    }
    double dsum = (double)(4.0f * eps * sum);
    #pragma unroll
    for (int off = 32; off > 0; off >>= 1)
        dsum += __shfl_down(dsum, off, 64);
    __shared__ double wsum[4];
    if ((threadIdx.x & 63) == 0) wsum[threadIdx.x >> 6] = dsum;
    __syncthreads();
    if (threadIdx.x == 0)
        partial[blockIdx.x] = wsum[0] + wsum[1] + wsum[2] + wsum[3];
}

__global__ __launch_bounds__(256) void reduce_kernel(
    const double* __restrict__ partial, int n, float* __restrict__ out)
{
    double s = 0.0;
    for (int i = threadIdx.x; i < n; i += 256)
        s += partial[i];
    #pragma unroll
    for (int off = 32; off > 0; off >>= 1)
        s += __shfl_down(s, off, 64);
    __shared__ double wsum[4];
    if ((threadIdx.x & 63) == 0) wsum[threadIdx.x >> 6] = s;
    __syncthreads();
    if (threadIdx.x == 0)
        out[0] = (float)(wsum[0] + wsum[1] + wsum[2] + wsum[3]);
}

extern "C" void kernel_launch(void* const* d_in, const int* in_sizes, int n_in,
                              void* d_out, int out_size, void* d_ws, size_t ws_size,
                              hipStream_t stream) {
    const float* x     = (const float*)d_in[0];
    const float* eps   = (const float*)d_in[1];
    const float* sigma = (const float*)d_in[2];
    const float* box   = (const float*)d_in[3];
    const vint4* ii    = (const vint4*)d_in[4];
    const vint4* jj    = (const vint4*)d_in[5];
    float* out = (float*)d_out;

    const int n_pairs = in_sizes[4];            // 8388608
    const int n_part  = in_sizes[0] / 3;        // 262144
    const int block = 256;

    const size_t packed_bytes = (size_t)n_part * 16;            // 4 MB

    if (ws_size >= packed_bytes + 65536) {
        const int grid = (n_pairs / 4) / block; // 8192 blocks
        float4* xp = (float4*)d_ws;
        double* partial = (double*)((char*)d_ws + packed_bytes);
        const int n3 = n_part * 3;
        repack_kernel<<<(n3 + block - 1) / block, block, 0, stream>>>(x, (float*)xp, n3);
        lj_gld_kernel<<<grid, block, 0, stream>>>(xp, eps, sigma, box, ii, jj, partial);
        reduce_kernel<<<1, block, 0, stream>>>(partial, grid, out);
    } else {
        const int grid = (n_pairs / 4) / block; // 8192 blocks
        double* partial = (double*)d_ws;
        lj_pairs3_kernel<<<grid, block, 0, stream>>>(x, eps, sigma, box, ii, jj, partial);
        reduce_kernel<<<1, block, 0, stream>>>(partial, grid, out);
    }
}